// Round 5
// baseline (28864.154 us; speedup 1.0000x reference)
//
#include <hip/hip_runtime.h>
#include <cstdint>
#include <cstddef>

// ============================================================================
// Persistent fused 2-layer LSTM + FC for MI355X (gfx950) — Round 5.
// R4 post-mortem: VGPR_Count pinned at exactly 128 across two different
// stagings => __launch_bounds__(512,2) was the cause (hipcc treats arg2 as
// min BLOCKS/CU: 2 blocks x 8 waves = 4 waves/SIMD -> 128-VGPR cap). The L1
// weight set (148 floats) cannot fit -> weights spilled to scratch in the
// K-loop (WRITE_SIZE 5.5->8.7 GB of scratch churn). R5 is the single-variable
// fix: __launch_bounds__(512,1) -> cap >= 256, no spill. LDS (143 KB) still
// forces 1 block/CU, so the real occupancy (2 waves/SIMD) is unchanged.
// Everything else identical to R4:
//   - 128 L0-blocks || 128 L1-blocks layer pipeline, 501 flat barriers.
//   - h in [t][j][b]: contiguous 128B/wave sc1 stores, LDS transpose 33/17.
//   - 4-wide batched gate reductions (independent butterfly chains).
// ============================================================================

#define NBLK 256
#define NTHR 512

namespace {
constexpr int kB = 32, kT = 512, kI = 256, kH = 1024, kO = 512, kTR = 500;
constexpr int kRounds = 502;                 // r = 0..501
constexpr size_t kBarFloats = 2048;          // flags[256]
constexpr size_t kH1Off = kBarFloats;        // h1_state[502][1024][32]
constexpr size_t kH1Len = (size_t)kRounds * kH * kB;
constexpr size_t kH2Off = kH1Off + kH1Len;   // h2_state[2][1024][32]
constexpr int kXchg = 34816;                 // gate-exchange region (1024 f)
constexpr int kLdsFloats = kXchg + 1024;
constexpr int kLdsBytes = kLdsFloats * 4;    // 143360 B -> 1 block/CU
}

typedef unsigned long long u64;

// ---------------------------------------------------------------------------
// Flat grid barrier (monotonic steps 1..501): each block release-stores its
// flag, then one wave polls ALL 256 flags (4/lane). Two LLC hops total.
// ---------------------------------------------------------------------------
__device__ __forceinline__ void grid_barrier(unsigned* flags, unsigned step) {
  __syncthreads();                      // drains vmcnt: h stores complete
  const int tid = threadIdx.x;
  if (tid < 64) {
    if (tid == 0)
      __hip_atomic_store(&flags[blockIdx.x], step, __ATOMIC_RELEASE,
                         __HIP_MEMORY_SCOPE_AGENT);
    const int l4 = tid << 2;
    bool done;
    do {
      unsigned ok = 1u;
#pragma unroll
      for (int k = 0; k < 4; ++k)
        ok &= (unsigned)(__hip_atomic_load(&flags[l4 + k], __ATOMIC_RELAXED,
                                           __HIP_MEMORY_SCOPE_AGENT) >= step);
      done = __all((int)ok);
      if (!done) __builtin_amdgcn_s_sleep(1);
    } while (!done);
  }
  if (tid == 0)
    (void)__hip_atomic_load(&flags[0], __ATOMIC_ACQUIRE,
                            __HIP_MEMORY_SCOPE_AGENT);
  __syncthreads();
}

// Merged 4-value butterfly: lane ends with total of a_{lane&3}.
__device__ __forceinline__ float merged_gate_reduce(float a0, float a1,
                                                    float a2, float a3,
                                                    int lane) {
  a0 += __shfl_xor(a0, 1); a1 += __shfl_xor(a1, 1);
  a2 += __shfl_xor(a2, 1); a3 += __shfl_xor(a3, 1);
  float v0 = (lane & 1) ? a1 : a0;
  float v1 = (lane & 1) ? a3 : a2;
  v0 += __shfl_xor(v0, 2); v1 += __shfl_xor(v1, 2);
  float u = (lane & 2) ? v1 : v0;
  u += __shfl_xor(u, 4);
  u += __shfl_xor(u, 8);
  u += __shfl_xor(u, 16);
  u += __shfl_xor(u, 32);
  return u;
}

__device__ __forceinline__ float wave_sum(float x) {
  x += __shfl_xor(x, 1);  x += __shfl_xor(x, 2);
  x += __shfl_xor(x, 4);  x += __shfl_xor(x, 8);
  x += __shfl_xor(x, 16); x += __shfl_xor(x, 32);
  return x;
}

__device__ __forceinline__ float sigmoid_f(float x) {
  return __builtin_amdgcn_rcpf(1.f + __expf(-x));
}
__device__ __forceinline__ float tanh_f(float x) {
  return 1.f - 2.f * __builtin_amdgcn_rcpf(1.f + __expf(2.f * x));
}

__device__ __forceinline__ u64 ld_agent_u64(const float* p) {
  return __hip_atomic_load((const u64*)p, __ATOMIC_RELAXED,
                           __HIP_MEMORY_SCOPE_AGENT);
}
__device__ __forceinline__ void st_agent_f32(float* p, float v) {
  __hip_atomic_store(p, v, __ATOMIC_RELAXED, __HIP_MEMORY_SCOPE_AGENT);
}
__device__ __forceinline__ float u64_lo(u64 v) {
  return __uint_as_float((unsigned)(v & 0xffffffffull));
}
__device__ __forceinline__ float u64_hi(u64 v) {
  return __uint_as_float((unsigned)(v >> 32));
}

__global__ void __launch_bounds__(256, 1) lstm_init_kernel(float* ws) {
  const size_t idx = (size_t)blockIdx.x * blockDim.x + threadIdx.x;
  if (idx < kBarFloats) ((unsigned*)ws)[idx] = 0u;
  if (idx < (size_t)kB * kH) {
    ws[kH1Off + idx] = 0.f;             // h1_state[0] = 0
    ws[kH2Off + idx] = 0.f;             // h2_state slot 0 = 0
  }
}

__global__ void __launch_bounds__(NTHR, 1) lstm_persist_kernel(
    const float* __restrict__ x,
    const float* __restrict__ Wih0, const float* __restrict__ Whh0,
    const float* __restrict__ bih0, const float* __restrict__ bhh0,
    const float* __restrict__ Wih1, const float* __restrict__ Whh1,
    const float* __restrict__ bih1, const float* __restrict__ bhh1,
    const float* __restrict__ Wfc, const float* __restrict__ bfc,
    float* __restrict__ out, float* __restrict__ ws) {
  const int tid = threadIdx.x;
  const int bk = blockIdx.x;
  const int w = tid >> 6;               // wave 0..7
  const int lane = tid & 63;
  unsigned* flags = (unsigned*)ws;
  float* h1s = ws + kH1Off;             // [502][1024][32]
  float* h2s = ws + kH2Off;             // [2][1024][32]
  extern __shared__ float lds[];

  if (bk < 128) {
    // ========================= Layer 0 =========================
    const int j0 = bk * 8 + w;          // owned hidden unit
    float whh[4][16], wih[4][4], bias[4];
#pragma unroll
    for (int g = 0; g < 4; ++g) {
#pragma unroll
      for (int c = 0; c < 16; ++c)
        whh[g][c] = Whh0[(size_t)(g * kH + j0) * kH + c * 64 + lane];
#pragma unroll
      for (int c = 0; c < 4; ++c)
        wih[g][c] = Wih0[(size_t)(g * kH + j0) * kI + c * 64 + lane];
      bias[g] = bih0[g * kH + j0] + bhh0[g * kH + j0];
    }
    float creg = 0.f;                   // c for (b=lane, j0), lanes 0..31

    for (int r = 0; r <= 500; ++r) {
      // ---- stage h1_state[r] ([j][b]) -> lds [k][b] stride 33, pipelined
      {
        const float* src = h1s + (size_t)r * (kH * kB);
        u64 c0 = ld_agent_u64(src + (size_t)(0 * NTHR + tid) * 2);
        u64 c1 = ld_agent_u64(src + (size_t)(1 * NTHR + tid) * 2);
        u64 c2 = ld_agent_u64(src + (size_t)(2 * NTHR + tid) * 2);
        u64 c3 = ld_agent_u64(src + (size_t)(3 * NTHR + tid) * 2);
        __syncthreads();                // prior-round LDS reads complete
#pragma unroll
        for (int i = 0; i < 32; i += 4) {
          u64 n0 = 0, n1 = 0, n2 = 0, n3 = 0;
          if (i + 4 < 32) {
            n0 = ld_agent_u64(src + (size_t)((i + 4) * NTHR + tid) * 2);
            n1 = ld_agent_u64(src + (size_t)((i + 5) * NTHR + tid) * 2);
            n2 = ld_agent_u64(src + (size_t)((i + 6) * NTHR + tid) * 2);
            n3 = ld_agent_u64(src + (size_t)((i + 7) * NTHR + tid) * 2);
          }
#pragma unroll
          for (int k = 0; k < 4; ++k) {
            const u64 v = (k == 0) ? c0 : (k == 1) ? c1 : (k == 2) ? c2 : c3;
            const int idx = (i + k) * NTHR + tid;
            const int j = idx >> 4, q = (idx & 15) * 2;
            lds[j * 33 + q]     = u64_lo(v);
            lds[j * 33 + q + 1] = u64_hi(v);
          }
          c0 = n0; c1 = n1; c2 = n2; c3 = n3;
        }
      }
      __syncthreads();

      // ---- gates, 4 batches per group (4 independent reduce chains)
      for (int bt = 0; bt < 32; bt += 4) {
        float xv[4][4];
#pragma unroll
        for (int bi = 0; bi < 4; ++bi) {
          const float* xp = x + ((size_t)(bt + bi) * kT + r) * kI + lane;
          xv[bi][0] = xp[0];   xv[bi][1] = xp[64];
          xv[bi][2] = xp[128]; xv[bi][3] = xp[192];
        }
        float acc[4][4];
#pragma unroll
        for (int bi = 0; bi < 4; ++bi) {
          float a0 = 0.f, a1 = 0.f, a2 = 0.f, a3 = 0.f;
#pragma unroll
          for (int c = 0; c < 16; ++c) {
            const float hv = lds[(c * 64 + lane) * 33 + bt + bi];
            a0 = fmaf(hv, whh[0][c], a0);
            a1 = fmaf(hv, whh[1][c], a1);
            a2 = fmaf(hv, whh[2][c], a2);
            a3 = fmaf(hv, whh[3][c], a3);
          }
#pragma unroll
          for (int c = 0; c < 4; ++c) {
            a0 = fmaf(xv[bi][c], wih[0][c], a0);
            a1 = fmaf(xv[bi][c], wih[1][c], a1);
            a2 = fmaf(xv[bi][c], wih[2][c], a2);
            a3 = fmaf(xv[bi][c], wih[3][c], a3);
          }
          acc[bi][0] = a0; acc[bi][1] = a1; acc[bi][2] = a2; acc[bi][3] = a3;
        }
        const float u0 = merged_gate_reduce(acc[0][0], acc[0][1], acc[0][2],
                                            acc[0][3], lane);
        const float u1 = merged_gate_reduce(acc[1][0], acc[1][1], acc[1][2],
                                            acc[1][3], lane);
        const float u2 = merged_gate_reduce(acc[2][0], acc[2][1], acc[2][2],
                                            acc[2][3], lane);
        const float u3 = merged_gate_reduce(acc[3][0], acc[3][1], acc[3][2],
                                            acc[3][3], lane);
        const float sel = (lane & 8) ? ((lane & 4) ? u3 : u2)
                                     : ((lane & 4) ? u1 : u0);
        if (lane < 16) lds[kXchg + w * 128 + bt * 4 + lane] = sel;
      }
      if (lane < kB) {                  // gate math for batch b=lane
        const float4 g4 = *(const float4*)&lds[kXchg + w * 128 + lane * 4];
        const float gi = sigmoid_f(g4.x + bias[0]);
        const float gf = sigmoid_f(g4.y + bias[1]);
        const float gg = tanh_f(g4.z + bias[2]);
        const float go = sigmoid_f(g4.w + bias[3]);
        creg = gf * creg + gi * gg;
        const float hnew = go * tanh_f(creg);
        st_agent_f32(&h1s[(size_t)(r + 1) * (kH * kB) + j0 * kB + lane],
                     hnew);
      }
      grid_barrier(flags, (unsigned)(r + 1));
    }
  } else {
    // ==================== Layer 1 + fused FC ====================
    const int bl = bk - 128;
    const int j1 = bl * 8 + w;
    float wih[4][16], whh[4][16], bias[4], wfc[16];
#pragma unroll
    for (int g = 0; g < 4; ++g) {
#pragma unroll
      for (int c = 0; c < 16; ++c) {
        wih[g][c] = Wih1[(size_t)(g * kH + j1) * kH + c * 64 + lane];
        whh[g][c] = Whh1[(size_t)(g * kH + j1) * kH + c * 64 + lane];
      }
      bias[g] = bih1[g * kH + j1] + bhh1[g * kH + j1];
    }
    const bool fcw = (w < 4);           // waves 0-3 own FC col bl*4+w
    float bfco = 0.f;
#pragma unroll
    for (int c = 0; c < 16; ++c)
      wfc[c] = fcw ? Wfc[(size_t)(bl * 4 + w) * kH + c * 64 + lane] : 0.f;
    if (fcw) bfco = bfc[bl * 4 + w];
    float creg0 = 0.f, creg1 = 0.f;     // c for b=lane(half0), b=16+lane
    float* ldsH1 = lds;                 // [k][b-half], stride 17
    float* ldsH2 = lds + 17408;

    grid_barrier(flags, 1u);            // round 0: no L1 work
    for (int r = 1; r <= 501; ++r) {
      const float* s1 = h1s + (size_t)r * (kH * kB);
      const float* s2 = h2s + (size_t)((r - 1) & 1) * (kH * kB);
#pragma unroll
      for (int half = 0; half < 2; ++half) {
        // ---- stage h1[r] & h2[r-1] halves, pipelined (8 u64 in flight)
        {
          const float* p1 = s1 + half * 16;
          const float* p2 = s2 + half * 16;
          u64 a0, a1, b0, b1;
          {
            const int i0 = 0 * NTHR + tid, i1 = 1 * NTHR + tid;
            a0 = ld_agent_u64(p1 + (i0 >> 3) * kB + (i0 & 7) * 2);
            a1 = ld_agent_u64(p1 + (i1 >> 3) * kB + (i1 & 7) * 2);
            b0 = ld_agent_u64(p2 + (i0 >> 3) * kB + (i0 & 7) * 2);
            b1 = ld_agent_u64(p2 + (i1 >> 3) * kB + (i1 & 7) * 2);
          }
          __syncthreads();              // previous compute's LDS reads done
#pragma unroll
          for (int i = 0; i < 16; i += 2) {
            u64 na0 = 0, na1 = 0, nb0 = 0, nb1 = 0;
            if (i + 2 < 16) {
              const int i0 = (i + 2) * NTHR + tid, i1 = (i + 3) * NTHR + tid;
              na0 = ld_agent_u64(p1 + (i0 >> 3) * kB + (i0 & 7) * 2);
              na1 = ld_agent_u64(p1 + (i1 >> 3) * kB + (i1 & 7) * 2);
              nb0 = ld_agent_u64(p2 + (i0 >> 3) * kB + (i0 & 7) * 2);
              nb1 = ld_agent_u64(p2 + (i1 >> 3) * kB + (i1 & 7) * 2);
            }
#pragma unroll
            for (int k = 0; k < 2; ++k) {
              const u64 va = k ? a1 : a0;
              const u64 vb = k ? b1 : b0;
              const int idx = (i + k) * NTHR + tid;
              const int j = idx >> 3, q = (idx & 7) * 2;
              ldsH1[j * 17 + q]     = u64_lo(va);
              ldsH1[j * 17 + q + 1] = u64_hi(va);
              ldsH2[j * 17 + q]     = u64_lo(vb);
              ldsH2[j * 17 + q + 1] = u64_hi(vb);
            }
            a0 = na0; a1 = na1; b0 = nb0; b1 = nb1;
          }
        }
        __syncthreads();

        float myfc = 0.f;
        for (int bt = 0; bt < 16; bt += 4) {
          float acc[4][4], fcc[4];
#pragma unroll
          for (int bi = 0; bi < 4; ++bi) {
            const int b2 = bt + bi;
            float a0 = 0.f, a1 = 0.f, a2 = 0.f, a3 = 0.f, a4 = 0.f;
#pragma unroll
            for (int c = 0; c < 16; ++c) {        // input part: h1[r]
              const float hv = ldsH1[(c * 64 + lane) * 17 + b2];
              a0 = fmaf(hv, wih[0][c], a0);
              a1 = fmaf(hv, wih[1][c], a1);
              a2 = fmaf(hv, wih[2][c], a2);
              a3 = fmaf(hv, wih[3][c], a3);
            }
#pragma unroll
            for (int c = 0; c < 16; ++c) {        // recurrent: h2[r-1]
              const float gv = ldsH2[(c * 64 + lane) * 17 + b2];
              a0 = fmaf(gv, whh[0][c], a0);
              a1 = fmaf(gv, whh[1][c], a1);
              a2 = fmaf(gv, whh[2][c], a2);
              a3 = fmaf(gv, whh[3][c], a3);
              a4 = fmaf(gv, wfc[c], a4);          // fused FC (wfc=0 if !fcw)
            }
            acc[bi][0] = a0; acc[bi][1] = a1;
            acc[bi][2] = a2; acc[bi][3] = a3;
            fcc[bi] = a4;
          }
          const float u0 = merged_gate_reduce(acc[0][0], acc[0][1],
                                              acc[0][2], acc[0][3], lane);
          const float u1 = merged_gate_reduce(acc[1][0], acc[1][1],
                                              acc[1][2], acc[1][3], lane);
          const float u2 = merged_gate_reduce(acc[2][0], acc[2][1],
                                              acc[2][2], acc[2][3], lane);
          const float u3 = merged_gate_reduce(acc[3][0], acc[3][1],
                                              acc[3][2], acc[3][3], lane);
          const float sel = (lane & 8) ? ((lane & 4) ? u3 : u2)
                                       : ((lane & 4) ? u1 : u0);
          if (lane < 16) lds[kXchg + w * 64 + bt * 4 + lane] = sel;
          if (fcw) {
            const float f0 = wave_sum(fcc[0]);
            const float f1 = wave_sum(fcc[1]);
            const float f2 = wave_sum(fcc[2]);
            const float f3 = wave_sum(fcc[3]);
            const int d = lane - bt;
            if (d >= 0 && d < 4)
              myfc = (d == 0) ? f0 : (d == 1) ? f1 : (d == 2) ? f2 : f3;
          }
        }
        if (lane < 16) {                // gate math for b = half*16+lane
          const float4 g4 = *(const float4*)&lds[kXchg + w * 64 + lane * 4];
          const float gi = sigmoid_f(g4.x + bias[0]);
          const float gf = sigmoid_f(g4.y + bias[1]);
          const float gg = tanh_f(g4.z + bias[2]);
          const float go = sigmoid_f(g4.w + bias[3]);
          float cr = half ? creg1 : creg0;
          cr = gf * cr + gi * gg;
          if (half) creg1 = cr; else creg0 = cr;
          const float hnew = go * tanh_f(cr);
          st_agent_f32(&h2s[(size_t)(r & 1) * (kH * kB) + j1 * kB +
                            half * 16 + lane], hnew);
        }
        if (fcw && r >= 2 && lane < 16) {
          const int b = half * 16 + lane;
          out[((size_t)b * kTR + (r - 2)) * kO + bl * 4 + w] = myfc + bfco;
        }
      }
      if (r <= 500) grid_barrier(flags, (unsigned)(r + 1));
    }
  }
}

extern "C" void kernel_launch(void* const* d_in, const int* in_sizes, int n_in,
                              void* d_out, int out_size, void* d_ws,
                              size_t ws_size, hipStream_t stream) {
  const float* x    = (const float*)d_in[0];
  const float* Wih0 = (const float*)d_in[1];
  const float* Whh0 = (const float*)d_in[2];
  const float* bih0 = (const float*)d_in[3];
  const float* bhh0 = (const float*)d_in[4];
  const float* Wih1 = (const float*)d_in[5];
  const float* Whh1 = (const float*)d_in[6];
  const float* bih1 = (const float*)d_in[7];
  const float* bhh1 = (const float*)d_in[8];
  const float* Wfc  = (const float*)d_in[9];
  const float* bfc  = (const float*)d_in[10];
  float* out = (float*)d_out;
  float* ws  = (float*)d_ws;

  (void)hipFuncSetAttribute((const void*)lstm_persist_kernel,
                            hipFuncAttributeMaxDynamicSharedMemorySize,
                            kLdsBytes);

  hipLaunchKernelGGL(lstm_init_kernel, dim3(128), dim3(256), 0, stream, ws);
  hipLaunchKernelGGL(lstm_persist_kernel, dim3(NBLK), dim3(NTHR), kLdsBytes,
                     stream, x, Wih0, Whh0, bih0, bhh0, Wih1, Whh1, bih1,
                     bhh1, Wfc, bfc, out, ws);
}

// Round 6
// 12252.571 us; speedup vs baseline: 2.3558x; 2.3558x over previous
//
#include <hip/hip_runtime.h>
#include <cstdint>
#include <cstddef>

// ============================================================================
// Persistent fused 2-layer LSTM + FC for MI355X (gfx950) — Round 6: MFMA.
// R5 post-mortem: fp32-weights-in-VGPR cannot fit (108 regs/lane chip-wide,
// 128-reg compiler pin at 512thr) AND the 6-hop shuffle reduction per gate
// output (~1.7M ops/round) is a VALU wall. v_mfma_f32_16x16x32_f16 fixes
// both: HW reduction, f16 weights (68 VGPR/wave), ~34 MFMA/wave/round.
//   - All 256 blocks handle L0+L1+FC slices (no split, zero duplication).
//   - M-tile = 4 units x 4 gates; D-layout row=(lane>>4)*4+reg => all 4
//     gates of a unit land in ONE lane: in-lane gate math, c-state in regs.
//   - K split across 8 waves (chunks w+8i); partials ds_add_f32 into LDS.
//   - h state f16, global layout [r][b][u] (fresh addresses per round ->
//     plain-address safety; sc1 stores/loads as in R2-R5). Stage = straight
//     u64 copy to LDS [b][u+pad]; B-frags = ds_read_b128 of 8 consec k=u.
//   - Rounds r=1..502: L0: h1[r] = step(h1[r-1], x[r-1]);
//     L1: h2[r-1] = step(h2[r-2], h1[r-1]); FC: out[r-3] = Wfc*h2[r-2]+b.
//     One staged pair (h1[r-1], h2[r-2]) serves L0-rec, L1-in, L1-rec, FC.
// ============================================================================

#define NBLK 256
#define NTHR 512

typedef _Float16 f16;
typedef _Float16 f16x8 __attribute__((ext_vector_type(8)));
typedef float f32x4 __attribute__((ext_vector_type(4)));
typedef unsigned long long u64;

namespace {
constexpr int kB = 32, kT = 512, kI = 256, kH = 1024, kO = 512, kTR = 500;
constexpr int kRounds = 502;
// workspace layout (bytes)
constexpr size_t kH1Off = 4096;                      // flags in [0,4096)
constexpr size_t kH1Bytes = 503ull * kB * kH * 2;    // h1 f16 [503][32][1024]
constexpr size_t kH2Off = kH1Off + kH1Bytes;         // h2 f16 [502][32][1024]
// LDS: h1 stage [32][1032] f16 | h2 stage same | zone 6*16*17 f32
constexpr int kStageRow = 1032;                      // f16 per b-row (pad 8)
constexpr int kH2Lds = kB * kStageRow;               // f16 index 33024
constexpr int kZoneBytes = 6 * 16 * 17 * 4;          // 6528
constexpr int kLdsBytes = 2 * kB * kStageRow * 2 + kZoneBytes;  // 138624
}

// ---------------------------------------------------------------------------
__device__ __forceinline__ void grid_barrier(unsigned* flags, unsigned step) {
  __syncthreads();
  const int tid = threadIdx.x;
  if (tid < 64) {
    if (tid == 0)
      __hip_atomic_store(&flags[blockIdx.x], step, __ATOMIC_RELEASE,
                         __HIP_MEMORY_SCOPE_AGENT);
    const int l4 = tid << 2;
    bool done;
    do {
      unsigned ok = 1u;
#pragma unroll
      for (int k = 0; k < 4; ++k)
        ok &= (unsigned)(__hip_atomic_load(&flags[l4 + k], __ATOMIC_RELAXED,
                                           __HIP_MEMORY_SCOPE_AGENT) >= step);
      done = __all((int)ok);
      if (!done) __builtin_amdgcn_s_sleep(1);
    } while (!done);
  }
  if (tid == 0)
    (void)__hip_atomic_load(&flags[0], __ATOMIC_ACQUIRE,
                            __HIP_MEMORY_SCOPE_AGENT);
  __syncthreads();
}

__device__ __forceinline__ float sigmoid_f(float x) {
  return __builtin_amdgcn_rcpf(1.f + __expf(-x));
}
__device__ __forceinline__ float tanh_f(float x) {
  return 1.f - 2.f * __builtin_amdgcn_rcpf(1.f + __expf(2.f * x));
}
__device__ __forceinline__ u64 ld_agent_u64(const void* p) {
  return __hip_atomic_load((const u64*)p, __ATOMIC_RELAXED,
                           __HIP_MEMORY_SCOPE_AGENT);
}
__device__ __forceinline__ void st_agent_f16(f16* p, float v) {
  f16 hv = (f16)v;
  unsigned short us;
  __builtin_memcpy(&us, &hv, 2);
  __hip_atomic_store((unsigned short*)p, us, __ATOMIC_RELAXED,
                     __HIP_MEMORY_SCOPE_AGENT);
}
__device__ __forceinline__ f16x8 load8(const float* p) {
  f16x8 r;
#pragma unroll
  for (int j = 0; j < 8; ++j) r[j] = (f16)p[j];
  return r;
}

__global__ void __launch_bounds__(256, 1) lstm_init_kernel(char* ws) {
  const int idx = blockIdx.x * 256 + threadIdx.x;     // 32768 threads
  unsigned* flags = (unsigned*)ws;
  if (idx < 1024) flags[idx] = 0u;
  if (idx < 16384) {                                  // zero slot 0 (32768 f16)
    ((unsigned*)(ws + kH1Off))[idx] = 0u;
    ((unsigned*)(ws + kH2Off))[idx] = 0u;
  }
}

__global__ void __launch_bounds__(NTHR, 1) __attribute__((amdgpu_waves_per_eu(2)))
lstm_mfma_kernel(const float* __restrict__ x,
                 const float* __restrict__ Wih0, const float* __restrict__ Whh0,
                 const float* __restrict__ bih0, const float* __restrict__ bhh0,
                 const float* __restrict__ Wih1, const float* __restrict__ Whh1,
                 const float* __restrict__ bih1, const float* __restrict__ bhh1,
                 const float* __restrict__ Wfc, const float* __restrict__ bfc,
                 float* __restrict__ out, char* __restrict__ ws) {
  const int tid = threadIdx.x;
  const int bk = blockIdx.x;
  const int w = tid >> 6;                 // wave 0..7
  const int lane = tid & 63;
  const int m = lane & 15;                // A row / B col / D col
  const int kg = lane >> 4;               // k-group 0..3 (k = kg*8 + j)
  const int q = m >> 2, g = m & 3;        // A-row -> (unit-in-tile, gate)
  const int U0 = bk * 4;                  // owned unit base (both layers)

  unsigned* flags = (unsigned*)ws;
  f16* h1g = (f16*)(ws + kH1Off);         // [503][32][1024]
  f16* h2g = (f16*)(ws + kH2Off);         // [502][32][1024]
  extern __shared__ f16 lds[];
  float* zone = (float*)((char*)lds + 2 * kB * kStageRow * 2);  // 6*272 f32

  // ---- one-time A-fragment (weight) preload, f16 in VGPRs ----
  // A[m][k]: m = lane&15, k = kc*32 + (lane>>4)*8 + j   [m120 layout]
  f16x8 wL0[5], wL1[8], wFC[4];
#pragma unroll
  for (int i = 0; i < 4; ++i)             // L0 rec chunks (K 0..1023 of Whh0)
    wL0[i] = load8(Whh0 + (size_t)(g * kH + U0 + q) * kH + (w + 8 * i) * 32 + kg * 8);
  wL0[4] = load8(Wih0 + (size_t)(g * kH + U0 + q) * kI + w * 32 + kg * 8);
#pragma unroll
  for (int i = 0; i < 4; ++i)             // L1 input chunks (Wih1, K=h1)
    wL1[i] = load8(Wih1 + (size_t)(g * kH + U0 + q) * kH + (w + 8 * i) * 32 + kg * 8);
#pragma unroll
  for (int i = 4; i < 8; ++i)             // L1 rec chunks (Whh1, K=h2)
    wL1[i] = load8(Whh1 + (size_t)(g * kH + U0 + q) * kH + (w + 8 * (i - 4)) * 32 + kg * 8);
#pragma unroll
  for (int i = 0; i < 4; ++i) {           // FC rows: only m<2 valid (o=bk*2+m)
    f16x8 v = load8(Wfc + (size_t)(bk * 2 + (m < 2 ? m : 0)) * kH + (w + 8 * i) * 32 + kg * 8);
    if (m >= 2) {
#pragma unroll
      for (int j = 0; j < 8; ++j) v[j] = (f16)0.f;
    }
    wFC[i] = v;
  }
  // biases for finalize mapping: lane (qf = lane>>4, c = lane&15)
  const int qf = lane >> 4;
  float biasL0[4], biasL1[4];
#pragma unroll
  for (int j = 0; j < 4; ++j) {
    biasL0[j] = bih0[j * kH + U0 + qf] + bhh0[j * kH + U0 + qf];
    biasL1[j] = bih1[j * kH + U0 + qf] + bhh1[j * kH + U0 + qf];
  }
  const float bfc0 = bfc[bk * 2], bfc1 = bfc[bk * 2 + 1];
  float cL0a = 0.f, cL0b = 0.f, cL1a = 0.f, cL1b = 0.f;  // c-state (wave 0/1)

  for (int r = 1; r <= kRounds; ++r) {
    // ---- zero reduction zone (overlaps staging load latency)
    for (int i = tid; i < 6 * 272; i += NTHR) zone[i] = 0.f;
    // ---- stage h1[r-1], h2[max(r-2,0)]: straight u64 copy, 4-deep pipeline
    {
      const f16* s1 = h1g + (size_t)(r - 1) * (kB * kH);
      const f16* s2 = h2g + (size_t)(r >= 2 ? r - 2 : 0) * (kB * kH);
#pragma unroll
      for (int ii = 0; ii < 16; ii += 4) {
        u64 a[4], b[4];
#pragma unroll
        for (int k2 = 0; k2 < 4; ++k2) {
          const int idx = (ii + k2) * NTHR + tid;
          a[k2] = ld_agent_u64(s1 + idx * 4);
          b[k2] = ld_agent_u64(s2 + idx * 4);
        }
#pragma unroll
        for (int k2 = 0; k2 < 4; ++k2) {
          const int idx = (ii + k2) * NTHR + tid;
          const int bb = idx >> 8, uu = (idx & 255) * 4;
          *(u64*)(lds + bb * kStageRow + uu) = a[k2];
          *(u64*)(lds + kH2Lds + bb * kStageRow + uu) = b[k2];
        }
      }
    }
    __syncthreads();

    // ================= MFMA sections (K chunks w, w+8, ...) =================
    // ---- L0: D = Whh0 @ h1[r-1]  +  Wih0 @ x[r-1]
    {
      f32x4 a0 = {0.f, 0.f, 0.f, 0.f}, a1 = {0.f, 0.f, 0.f, 0.f};
#pragma unroll
      for (int i = 0; i < 4; ++i) {
        const int k = (w + 8 * i) * 32 + kg * 8;
        f16x8 b0 = *(const f16x8*)(lds + m * kStageRow + k);
        f16x8 b1 = *(const f16x8*)(lds + (16 + m) * kStageRow + k);
        a0 = __builtin_amdgcn_mfma_f32_16x16x32_f16(wL0[i], b0, a0, 0, 0, 0);
        a1 = __builtin_amdgcn_mfma_f32_16x16x32_f16(wL0[i], b1, a1, 0, 0, 0);
      }
      {  // x chunk: K' = w*32 .. w*32+31 of I=256
        const int kp = w * 32 + kg * 8;
        const float* xp0 = x + ((size_t)m * kT + (r - 1)) * kI + kp;
        f16x8 b0 = load8(xp0);
        f16x8 b1 = load8(xp0 + (size_t)16 * kT * kI);
        a0 = __builtin_amdgcn_mfma_f32_16x16x32_f16(wL0[4], b0, a0, 0, 0, 0);
        a1 = __builtin_amdgcn_mfma_f32_16x16x32_f16(wL0[4], b1, a1, 0, 0, 0);
      }
#pragma unroll
      for (int j = 0; j < 4; ++j) {
        atomicAdd(&zone[0 * 272 + (kg * 4 + j) * 17 + m], a0[j]);
        atomicAdd(&zone[1 * 272 + (kg * 4 + j) * 17 + m], a1[j]);
      }
    }
    // ---- L1: D = Wih1 @ h1[r-1]  +  Whh1 @ h2[r-2]
    {
      f32x4 a0 = {0.f, 0.f, 0.f, 0.f}, a1 = {0.f, 0.f, 0.f, 0.f};
#pragma unroll
      for (int i = 0; i < 4; ++i) {
        const int k = (w + 8 * i) * 32 + kg * 8;
        f16x8 b0 = *(const f16x8*)(lds + m * kStageRow + k);
        f16x8 b1 = *(const f16x8*)(lds + (16 + m) * kStageRow + k);
        a0 = __builtin_amdgcn_mfma_f32_16x16x32_f16(wL1[i], b0, a0, 0, 0, 0);
        a1 = __builtin_amdgcn_mfma_f32_16x16x32_f16(wL1[i], b1, a1, 0, 0, 0);
      }
#pragma unroll
      for (int i = 4; i < 8; ++i) {
        const int k = (w + 8 * (i - 4)) * 32 + kg * 8;
        f16x8 b0 = *(const f16x8*)(lds + kH2Lds + m * kStageRow + k);
        f16x8 b1 = *(const f16x8*)(lds + kH2Lds + (16 + m) * kStageRow + k);
        a0 = __builtin_amdgcn_mfma_f32_16x16x32_f16(wL1[i], b0, a0, 0, 0, 0);
        a1 = __builtin_amdgcn_mfma_f32_16x16x32_f16(wL1[i], b1, a1, 0, 0, 0);
      }
#pragma unroll
      for (int j = 0; j < 4; ++j) {
        atomicAdd(&zone[2 * 272 + (kg * 4 + j) * 17 + m], a0[j]);
        atomicAdd(&zone[3 * 272 + (kg * 4 + j) * 17 + m], a1[j]);
      }
    }
    // ---- FC: D = Wfc @ h2[r-2]   (rows 0,1 valid; rest zero weights)
    {
      f32x4 a0 = {0.f, 0.f, 0.f, 0.f}, a1 = {0.f, 0.f, 0.f, 0.f};
#pragma unroll
      for (int i = 0; i < 4; ++i) {
        const int k = (w + 8 * i) * 32 + kg * 8;
        f16x8 b0 = *(const f16x8*)(lds + kH2Lds + m * kStageRow + k);
        f16x8 b1 = *(const f16x8*)(lds + kH2Lds + (16 + m) * kStageRow + k);
        a0 = __builtin_amdgcn_mfma_f32_16x16x32_f16(wFC[i], b0, a0, 0, 0, 0);
        a1 = __builtin_amdgcn_mfma_f32_16x16x32_f16(wFC[i], b1, a1, 0, 0, 0);
      }
#pragma unroll
      for (int j = 0; j < 2; ++j) {       // only rows 0,1 needed
        if (kg == 0) {
          atomicAdd(&zone[4 * 272 + j * 17 + m], a0[j]);
          atomicAdd(&zone[5 * 272 + j * 17 + m], a1[j]);
        }
      }
    }
    __syncthreads();

    // ================= finalize (waves 0/1/2) =================
    if (w == 0) {                          // L0 gate math -> h1[r]
      const int c = lane & 15;
#pragma unroll
      for (int nt = 0; nt < 2; ++nt) {
        const float* z = zone + nt * 272;
        const float pi = z[(4 * qf + 0) * 17 + c] + biasL0[0];
        const float pf = z[(4 * qf + 1) * 17 + c] + biasL0[1];
        const float pg = z[(4 * qf + 2) * 17 + c] + biasL0[2];
        const float po = z[(4 * qf + 3) * 17 + c] + biasL0[3];
        float cc = nt ? cL0b : cL0a;
        cc = sigmoid_f(pf) * cc + sigmoid_f(pi) * tanh_f(pg);
        if (nt) cL0b = cc; else cL0a = cc;
        const float h = sigmoid_f(po) * tanh_f(cc);
        st_agent_f16(h1g + (size_t)r * (kB * kH) +
                     (size_t)(c + nt * 16) * kH + U0 + qf, h);
      }
    } else if (w == 1 && r >= 2) {         // L1 gate math -> h2[r-1]
      const int c = lane & 15;
#pragma unroll
      for (int nt = 0; nt < 2; ++nt) {
        const float* z = zone + (2 + nt) * 272;
        const float pi = z[(4 * qf + 0) * 17 + c] + biasL1[0];
        const float pf = z[(4 * qf + 1) * 17 + c] + biasL1[1];
        const float pg = z[(4 * qf + 2) * 17 + c] + biasL1[2];
        const float po = z[(4 * qf + 3) * 17 + c] + biasL1[3];
        float cc = nt ? cL1b : cL1a;
        cc = sigmoid_f(pf) * cc + sigmoid_f(pi) * tanh_f(pg);
        if (nt) cL1b = cc; else cL1a = cc;
        const float h = sigmoid_f(po) * tanh_f(cc);
        st_agent_f16(h2g + (size_t)(r - 1) * (kB * kH) +
                     (size_t)(c + nt * 16) * kH + U0 + qf, h);
      }
    } else if (w == 2 && r >= 3 && lane < 32) {  // FC -> out[:, r-3, :]
      const int b = lane;
      const float* z = zone + (4 + (lane >> 4)) * 272;
      const int c = lane & 15;
      float2 v;
      v.x = z[0 * 17 + c] + bfc0;
      v.y = z[1 * 17 + c] + bfc1;
      *(float2*)(out + ((size_t)b * kTR + (r - 3)) * kO + bk * 2) = v;
    }
    grid_barrier(flags, (unsigned)r);
  }
}

extern "C" void kernel_launch(void* const* d_in, const int* in_sizes, int n_in,
                              void* d_out, int out_size, void* d_ws,
                              size_t ws_size, hipStream_t stream) {
  const float* x    = (const float*)d_in[0];
  const float* Wih0 = (const float*)d_in[1];
  const float* Whh0 = (const float*)d_in[2];
  const float* bih0 = (const float*)d_in[3];
  const float* bhh0 = (const float*)d_in[4];
  const float* Wih1 = (const float*)d_in[5];
  const float* Whh1 = (const float*)d_in[6];
  const float* bih1 = (const float*)d_in[7];
  const float* bhh1 = (const float*)d_in[8];
  const float* Wfc  = (const float*)d_in[9];
  const float* bfc  = (const float*)d_in[10];
  float* out = (float*)d_out;
  char* ws   = (char*)d_ws;

  (void)hipFuncSetAttribute((const void*)lstm_mfma_kernel,
                            hipFuncAttributeMaxDynamicSharedMemorySize,
                            kLdsBytes);

  hipLaunchKernelGGL(lstm_init_kernel, dim3(128), dim3(256), 0, stream, ws);
  hipLaunchKernelGGL(lstm_mfma_kernel, dim3(NBLK), dim3(NTHR), kLdsBytes,
                     stream, x, Wih0, Whh0, bih0, bhh0, Wih1, Whh1, bih1,
                     bhh1, Wfc, bfc, out, ws);
}